// Round 1
// baseline (2182.153 us; speedup 1.0000x reference)
//
#include <hip/hip_runtime.h>
#include <hip/hip_bf16.h>

#define NNODE 16384

// ======================= GEMM =======================
// C[M,Ncol] = epi( A[M,K] @ B[K,Ncol] + bias )   row-major, M = 16384 (grid.y*128)
// EPI: 0 none, 1 relu, 2 leaky(0.01). ACCUM: C += result. BNA: a -> a*scale[k]+shift[k]
template<int EPI, bool ACCUM, bool BNA>
__global__ __launch_bounds__(256)
void gemm_k(const float* __restrict__ A, const float* __restrict__ Bw,
            float* __restrict__ C, int Ncol, int K,
            const float* __restrict__ bias,
            const float* __restrict__ scale, const float* __restrict__ shift)
{
    __shared__ float As[16][128];
    __shared__ float Bs[16][64];
    const int bm = blockIdx.y * 128;
    const int bn = blockIdx.x * 64;
    const int tid = threadIdx.x;
    const int tx = tid & 15, ty = tid >> 4;
    float acc[8][4];
#pragma unroll
    for (int i = 0; i < 8; i++)
#pragma unroll
        for (int j = 0; j < 4; j++) acc[i][j] = 0.f;

    for (int k0 = 0; k0 < K; k0 += 16) {
        // A tile: 128 rows x 16 k, store transposed As[k][row]
#pragma unroll
        for (int i = 0; i < 2; i++) {
            int idx = tid * 2 + i;
            int row = idx >> 2;
            int k4  = (idx & 3) << 2;
            const float* ap = A + (size_t)(bm + row) * K + k0 + k4;
            float4 v = *reinterpret_cast<const float4*>(ap);
            if (BNA) {
                v.x = fmaf(v.x, scale[k0+k4+0], shift[k0+k4+0]);
                v.y = fmaf(v.y, scale[k0+k4+1], shift[k0+k4+1]);
                v.z = fmaf(v.z, scale[k0+k4+2], shift[k0+k4+2]);
                v.w = fmaf(v.w, scale[k0+k4+3], shift[k0+k4+3]);
            }
            As[k4+0][row] = v.x;
            As[k4+1][row] = v.y;
            As[k4+2][row] = v.z;
            As[k4+3][row] = v.w;
        }
        // B tile: 16 rows x 64 cols
        {
            int row = tid >> 4;
            int c4  = (tid & 15) << 2;
            int gn  = bn + c4;
            float4 v;
            if (gn + 3 < Ncol) {
                v = *reinterpret_cast<const float4*>(Bw + (size_t)(k0 + row) * Ncol + gn);
            } else {
                float t0 = (gn+0 < Ncol) ? Bw[(size_t)(k0+row)*Ncol + gn+0] : 0.f;
                float t1 = (gn+1 < Ncol) ? Bw[(size_t)(k0+row)*Ncol + gn+1] : 0.f;
                float t2 = (gn+2 < Ncol) ? Bw[(size_t)(k0+row)*Ncol + gn+2] : 0.f;
                float t3 = (gn+3 < Ncol) ? Bw[(size_t)(k0+row)*Ncol + gn+3] : 0.f;
                v = make_float4(t0, t1, t2, t3);
            }
            *reinterpret_cast<float4*>(&Bs[row][c4]) = v;
        }
        __syncthreads();
#pragma unroll
        for (int kk = 0; kk < 16; kk++) {
            float a0[8], b0[4];
#pragma unroll
            for (int i = 0; i < 8; i++) a0[i] = As[kk][ty*8 + i];
#pragma unroll
            for (int j = 0; j < 4; j++) b0[j] = Bs[kk][tx*4 + j];
#pragma unroll
            for (int i = 0; i < 8; i++)
#pragma unroll
                for (int j = 0; j < 4; j++) acc[i][j] = fmaf(a0[i], b0[j], acc[i][j]);
        }
        __syncthreads();
    }
#pragma unroll
    for (int i = 0; i < 8; i++) {
        int r = bm + ty*8 + i;
#pragma unroll
        for (int j = 0; j < 4; j++) {
            int c = bn + tx*4 + j;
            if (c < Ncol) {
                float v = acc[i][j];
                if (bias) v += bias[c];
                size_t off = (size_t)r * Ncol + c;
                if (ACCUM) v += C[off];
                if (EPI == 1) v = fmaxf(v, 0.f);
                if (EPI == 2) v = (v > 0.f) ? v : 0.01f * v;
                C[off] = v;
            }
        }
    }
}

// ======================= PNA aggregation =======================
// Per node v (block): 8 edges e=8v..8v+7, msg_c = Hsrc[src_e][c] + Hdst[v][c] + sum_j es[e][j]*Wme[j][c]
// (Hdst already contains +bm). Writes agg[v] = [ s | max | std ]  (3*cin wide)
__global__ void agg_k(const float* __restrict__ Hsrc, const float* __restrict__ Hdst,
                      const float* __restrict__ es, const int* __restrict__ src,
                      const float* __restrict__ Wme, float* __restrict__ agg, int cin)
{
    __shared__ float Wl[16][416];
    __shared__ float se[128];
    __shared__ int   ssrc[8];
    const int v = blockIdx.x;
    const int tid = threadIdx.x;
    for (int j = 0; j < 16; j++)
        for (int c = tid; c < cin; c += blockDim.x)
            Wl[j][c] = Wme[j * cin + c];
    for (int i = tid; i < 128; i += blockDim.x) se[i] = es[(size_t)v * 128 + i];
    if (tid < 8) ssrc[tid] = src[v * 8 + tid];
    __syncthreads();
    for (int c = tid; c < cin; c += blockDim.x) {
        float hd = Hdst[(size_t)v * cin + c];
        float sum = 0.f, sq = 0.f, mx = -INFINITY;
#pragma unroll
        for (int e = 0; e < 8; e++) {
            float m = hd + Hsrc[(size_t)ssrc[e] * cin + c];
            const float* ep = &se[e * 16];
#pragma unroll
            for (int j = 0; j < 16; j++) m = fmaf(ep[j], Wl[j][c], m);
            sum += m;
            sq = fmaf(m, m, sq);
            mx = fmaxf(mx, m);
        }
        float mean = sum * 0.125f;
        float msq  = sq * 0.125f;
        float stdv = sqrtf(fmaxf(msq - mean * mean, 0.f) + 1e-30f);
        size_t o = (size_t)v * 3 * cin;
        agg[o + c] = sum;
        agg[o + cin + c] = mx;
        agg[o + 2 * cin + c] = stdv;
    }
}

// ======================= Wu reorder: [5cin,cout] -> [3cin,cout] with mean folded into s ====
__global__ void prep_wuagg(const float* __restrict__ Wu, float* __restrict__ Wa, int cin, int cout)
{
    int idx = blockIdx.x * blockDim.x + threadIdx.x;
    int total = 3 * cin * cout;
    if (idx >= total) return;
    int row = idx / cout, c = idx % cout;
    float v;
    if (row < cin)            v = Wu[(size_t)(cin + row) * cout + c] * 0.125f + Wu[(size_t)(3*cin + row) * cout + c];
    else if (row < 2 * cin)   v = Wu[(size_t)(2*cin + (row - cin)) * cout + c];
    else                      v = Wu[(size_t)(4*cin + (row - 2*cin)) * cout + c];
    Wa[idx] = v;
}

// ======================= BatchNorm stats (deterministic 2-stage) =======================
__global__ void bnstats1_k(const float* __restrict__ u, float* __restrict__ part, int cout)
{
    int c = threadIdx.x;
    if (c >= cout) return;
    int r0 = blockIdx.x * 256;
    float s = 0.f, q = 0.f;
    for (int r = r0; r < r0 + 256; r++) {
        float v = u[(size_t)r * cout + c];
        s += v;
        q = fmaf(v, v, q);
    }
    part[(size_t)blockIdx.x * cout + c] = s;
    part[(size_t)(64 + blockIdx.x) * cout + c] = q;
}

__global__ void bnstats2_k(const float* __restrict__ part, const float* __restrict__ bng,
                           const float* __restrict__ bnb, float* __restrict__ scale,
                           float* __restrict__ shift, int cout)
{
    int c = threadIdx.x;
    if (c >= cout) return;
    float s = 0.f, q = 0.f;
    for (int b = 0; b < 64; b++) { s += part[(size_t)b * cout + c]; q += part[(size_t)(64 + b) * cout + c]; }
    float mean = s / 16384.f;
    float var  = q / 16384.f - mean * mean;
    float sc   = bng[c] / sqrtf(var + 1e-5f);
    scale[c] = sc;
    shift[c] = bnb[c] - mean * sc;
}

// ======================= concat [h1 | d2] =======================
__global__ void concat_k(const float* __restrict__ h1, const float* __restrict__ d2,
                         float* __restrict__ hin2)
{
    int r = blockIdx.x, c = threadIdx.x;
    if (c < 384)      hin2[(size_t)r * 416 + c] = h1[(size_t)r * 384 + c];
    else if (c < 416) hin2[(size_t)r * 416 + c] = d2[(size_t)r * 32 + (c - 384)];
}

// ======================= row max over h3 (192) =======================
__global__ void rowmax_k(const float* __restrict__ h3, float* __restrict__ nm)
{
    int wave = threadIdx.x >> 6;
    int lane = threadIdx.x & 63;
    int node = blockIdx.x * 4 + wave;
    const float* row = h3 + (size_t)node * 192;
    float m = -INFINITY;
    for (int t = lane; t < 192; t += 64) m = fmaxf(m, row[t]);
#pragma unroll
    for (int off = 32; off > 0; off >>= 1) m = fmaxf(m, __shfl_down(m, off, 64));
    if (lane == 0) nm[node] = m;
}

// ======================= gate MLP: g = sigmoid(relu(nm@W3+b3)@W4+b4) =======================
__global__ __launch_bounds__(256) void g_k(const float* __restrict__ nm,
    const float* __restrict__ W3, const float* __restrict__ b3,
    const float* __restrict__ W4, const float* __restrict__ b4,
    float* __restrict__ g)
{
    __shared__ float row[256];
    __shared__ float t1[64];
    int b = blockIdx.x, tid = threadIdx.x;
    row[tid] = nm[b * 256 + tid];
    __syncthreads();
    if (tid < 64) {
        float a = b3[tid];
        for (int k = 0; k < 256; k++) a = fmaf(row[k], W3[k * 64 + tid], a);
        t1[tid] = fmaxf(a, 0.f);
    }
    __syncthreads();
    float a = b4[tid];
    for (int j = 0; j < 64; j++) a = fmaf(t1[j], W4[j * 256 + tid], a);
    g[b * 256 + tid] = 1.f / (1.f + expf(-a));
}

// ======================= masked softmax over [B, 49152] =======================
__global__ __launch_bounds__(512) void softmax_k(const float* __restrict__ mask,
    const float* __restrict__ g, const float* __restrict__ h3, float* __restrict__ out)
{
    int b = blockIdx.x, tid = threadIdx.x;
    const size_t base = (size_t)b * 49152;
    __shared__ float red[512];
    float m = -INFINITY;
    for (int i = tid; i < 49152; i += 512) {
        float mk = mask[base + i];
        float v = (mk == 0.f) ? -1e5f : g[b * 256 + i / 192] * h3[base + i];
        m = fmaxf(m, v);
    }
    red[tid] = m; __syncthreads();
    for (int s = 256; s > 0; s >>= 1) { if (tid < s) red[tid] = fmaxf(red[tid], red[tid + s]); __syncthreads(); }
    m = red[0];
    __syncthreads();
    float z = 0.f;
    for (int i = tid; i < 49152; i += 512) {
        float mk = mask[base + i];
        float v = (mk == 0.f) ? -1e5f : g[b * 256 + i / 192] * h3[base + i];
        z += expf(v - m);
    }
    red[tid] = z; __syncthreads();
    for (int s = 256; s > 0; s >>= 1) { if (tid < s) red[tid] += red[tid + s]; __syncthreads(); }
    float invZ = 1.f / red[0];
    for (int i = tid; i < 49152; i += 512) {
        float mk = mask[base + i];
        float v = (mk == 0.f) ? -1e5f : g[b * 256 + i / 192] * h3[base + i];
        out[base + i] = expf(v - m) * invZ;
    }
}

// ======================= launcher =======================
extern "C" void kernel_launch(void* const* d_in, const int* in_sizes, int n_in,
                              void* d_out, int out_size, void* d_ws, size_t ws_size,
                              hipStream_t stream)
{
    const float* ns   = (const float*)d_in[0];
    const float* es   = (const float*)d_in[1];
    const float* dm   = (const float*)d_in[2];
    const float* mask = (const float*)d_in[3];
    const int*   src  = (const int*)d_in[4];
    const float* Wm1 = (const float*)d_in[6],  *bm1 = (const float*)d_in[7];
    const float* Wu1 = (const float*)d_in[8],  *bu1 = (const float*)d_in[9];
    const float* bng1= (const float*)d_in[10], *bnb1= (const float*)d_in[11];
    const float* Wx1 = (const float*)d_in[12], *bx1 = (const float*)d_in[13];
    const float* Wm2 = (const float*)d_in[14], *bm2 = (const float*)d_in[15];
    const float* Wu2 = (const float*)d_in[16], *bu2 = (const float*)d_in[17];
    const float* bng2= (const float*)d_in[18], *bnb2= (const float*)d_in[19];
    const float* Wx2 = (const float*)d_in[20], *bx2 = (const float*)d_in[21];
    const float* Wm3 = (const float*)d_in[22], *bm3 = (const float*)d_in[23];
    const float* Wu3 = (const float*)d_in[24], *bu3 = (const float*)d_in[25];
    const float* bng3= (const float*)d_in[26], *bnb3= (const float*)d_in[27];
    const float* Wx3 = (const float*)d_in[28], *bx3 = (const float*)d_in[29];
    const float* W1 = (const float*)d_in[30], *b1 = (const float*)d_in[31];
    const float* W2 = (const float*)d_in[32], *b2 = (const float*)d_in[33];
    const float* W3 = (const float*)d_in[34], *b3 = (const float*)d_in[35];
    const float* W4 = (const float*)d_in[36], *b4 = (const float*)d_in[37];
    float* out = (float*)d_out;

    const int N = NNODE;
    float* ws = (float*)d_ws;
    size_t o = 0;
    auto alloc = [&](size_t n) { float* p = ws + o; o += (n + 3) & ~(size_t)3; return p; };
    float* Hsrc = alloc((size_t)N * 416);
    float* Hdst = alloc((size_t)N * 416);
    float* agg  = alloc((size_t)N * 1248);
    float* u    = alloc((size_t)N * 384);
    float* hA   = alloc((size_t)N * 384);   // h1, then reused as h2
    float* hin2 = alloc((size_t)N * 416);
    float* h3   = alloc((size_t)N * 192);
    float* d2   = alloc((size_t)N * 32);
    float* WuA1 = alloc((size_t)384 * 384);
    float* WuA2 = alloc((size_t)1248 * 384);
    float* WuA3 = alloc((size_t)1152 * 192);
    float* part = alloc((size_t)128 * 384);
    float* scale= alloc(384);
    float* shift= alloc(384);
    float* nm   = alloc(N);
    float* gbuf = alloc(N);
    float* d2t  = agg;  // alias: dead before agg is first written

    dim3 blk(256);
    auto grd = [&](int Ncol) { return dim3((Ncol + 63) / 64, N / 128); };

    // fold Wu -> Wu_agg  (s' = mean/8 + s, mx, std)
    prep_wuagg<<<(3*128*384 + 255)/256, 256, 0, stream>>>(Wu1, WuA1, 128, 384);
    prep_wuagg<<<(3*416*384 + 255)/256, 256, 0, stream>>>(Wu2, WuA2, 416, 384);
    prep_wuagg<<<(3*384*192 + 255)/256, 256, 0, stream>>>(Wu3, WuA3, 384, 192);

    // d2 = (dm@W1+b1)@W2+b2
    gemm_k<0,false,false><<<grd(64), blk, 0, stream>>>(dm, W1, d2t, 64, 256, b1, nullptr, nullptr);
    gemm_k<0,false,false><<<grd(32), blk, 0, stream>>>(d2t, W2, d2, 32, 64, b2, nullptr, nullptr);

    // ---------------- layer 1: h=ns, cin=128, cout=384 ----------------
    gemm_k<0,false,false><<<grd(128), blk, 0, stream>>>(ns, Wm1,            Hsrc, 128, 128, nullptr, nullptr, nullptr);
    gemm_k<0,false,false><<<grd(128), blk, 0, stream>>>(ns, Wm1 + 128*128,  Hdst, 128, 128, bm1, nullptr, nullptr);
    agg_k<<<N, 128, 0, stream>>>(Hsrc, Hdst, es, src, Wm1 + 2*128*128, agg, 128);
    gemm_k<0,false,false><<<grd(384), blk, 0, stream>>>(ns,  Wu1,  u, 384, 128, bu1, nullptr, nullptr);
    gemm_k<0,true ,false><<<grd(384), blk, 0, stream>>>(agg, WuA1, u, 384, 384, nullptr, nullptr, nullptr);
    bnstats1_k<<<64, 384, 0, stream>>>(u, part, 384);
    bnstats2_k<<<1, 384, 0, stream>>>(part, bng1, bnb1, scale, shift, 384);
    gemm_k<1,false,true><<<grd(384), blk, 0, stream>>>(u, Wx1, hA, 384, 384, bx1, scale, shift);

    concat_k<<<N, 448, 0, stream>>>(hA, d2, hin2);

    // ---------------- layer 2: h=hin2, cin=416, cout=384 ----------------
    gemm_k<0,false,false><<<grd(416), blk, 0, stream>>>(hin2, Wm2,           Hsrc, 416, 416, nullptr, nullptr, nullptr);
    gemm_k<0,false,false><<<grd(416), blk, 0, stream>>>(hin2, Wm2 + 416*416, Hdst, 416, 416, bm2, nullptr, nullptr);
    agg_k<<<N, 448, 0, stream>>>(Hsrc, Hdst, es, src, Wm2 + 2*416*416, agg, 416);
    gemm_k<0,false,false><<<grd(384), blk, 0, stream>>>(hin2, Wu2,  u, 384, 416,  bu2, nullptr, nullptr);
    gemm_k<0,true ,false><<<grd(384), blk, 0, stream>>>(agg,  WuA2, u, 384, 1248, nullptr, nullptr, nullptr);
    bnstats1_k<<<64, 384, 0, stream>>>(u, part, 384);
    bnstats2_k<<<1, 384, 0, stream>>>(part, bng2, bnb2, scale, shift, 384);
    gemm_k<1,false,true><<<grd(384), blk, 0, stream>>>(u, Wx2, hA, 384, 384, bx2, scale, shift);

    // ---------------- layer 3: h=hA(h2), cin=384, cout=192 ----------------
    gemm_k<0,false,false><<<grd(384), blk, 0, stream>>>(hA, Wm3,           Hsrc, 384, 384, nullptr, nullptr, nullptr);
    gemm_k<0,false,false><<<grd(384), blk, 0, stream>>>(hA, Wm3 + 384*384, Hdst, 384, 384, bm3, nullptr, nullptr);
    agg_k<<<N, 384, 0, stream>>>(Hsrc, Hdst, es, src, Wm3 + 2*384*384, agg, 384);
    gemm_k<0,false,false><<<grd(192), blk, 0, stream>>>(hA,  Wu3,  u, 192, 384,  bu3, nullptr, nullptr);
    gemm_k<0,true ,false><<<grd(192), blk, 0, stream>>>(agg, WuA3, u, 192, 1152, nullptr, nullptr, nullptr);
    bnstats1_k<<<64, 384, 0, stream>>>(u, part, 192);
    bnstats2_k<<<1, 384, 0, stream>>>(part, bng3, bnb3, scale, shift, 192);
    gemm_k<2,false,true><<<grd(192), blk, 0, stream>>>(u, Wx3, h3, 192, 192, bx3, scale, shift);

    // ---------------- head ----------------
    rowmax_k<<<N / 4, 256, 0, stream>>>(h3, nm);
    g_k<<<64, 256, 0, stream>>>(nm, W3, b3, W4, b4, gbuf);
    softmax_k<<<64, 512, 0, stream>>>(mask, gbuf, h3, out);
}

// Round 2
// 1097.505 us; speedup vs baseline: 1.9883x; 1.9883x over previous
//
#include <hip/hip_runtime.h>
#include <hip/hip_bf16.h>

#define NNODE 16384

typedef short v8s __attribute__((ext_vector_type(8)));
typedef float v4f __attribute__((ext_vector_type(4)));

__device__ __forceinline__ unsigned short f2bf(float v) {
    unsigned u = __float_as_uint(v);
    unsigned r = (u + 0x7FFF + ((u >> 16) & 1)) >> 16;
    return (unsigned short)r;
}
__device__ __forceinline__ float bf2f(unsigned short s) {
    return __uint_as_float(((unsigned)s) << 16);
}

// ======================= split-bf16 MFMA GEMM =======================
// C[M,Ncol] = epi( A[M,K] @ B[K,Ncol] + bias ), M=16384.
// B pre-split/transposed: Bh/Bl [Npad][Kpad] bf16 (Npad=Ncol here, Kpad=ceil64(K)).
// 3-product split: C ~= Ah*Bh + Al*Bh + Ah*Bl  (rel err ~1.5e-5)
// Tile 128x64, 4 waves (2x2), wave tile 64x32. LDS A tiles [128][64]bf16, st_16x32 swizzle.
template<int EPI, bool ACCUM, bool BNA>
__global__ __launch_bounds__(256, 2)
void mgemm(const float* __restrict__ A, const unsigned short* __restrict__ Bh,
           const unsigned short* __restrict__ Bl, float* __restrict__ C,
           int Ncol, int K, int Kpad, const float* __restrict__ bias,
           const float* __restrict__ scale, const float* __restrict__ shift)
{
    __shared__ __align__(16) unsigned short AhS[128 * 64];
    __shared__ __align__(16) unsigned short AlS[128 * 64];
    const int bm = blockIdx.y * 128;
    const int bn = blockIdx.x * 64;
    const int tid = threadIdx.x;
    const int lane = tid & 63, wid = tid >> 6;
    const int wm = wid >> 1, wn = wid & 1;
    const int r16 = lane & 15, q = lane >> 4;
    v4f acc[4][2];
#pragma unroll
    for (int i = 0; i < 4; i++)
#pragma unroll
        for (int j = 0; j < 2; j++) acc[i][j] = (v4f){0.f, 0.f, 0.f, 0.f};

    const int srow = tid >> 4;        // 0..15
    const int skl  = (tid & 15) * 4;  // 0..60
    const int Ksteps = (K + 63) >> 6;

    for (int step = 0; step < Ksteps; step++) {
        const int k0 = step << 6;
        // ---- stage A: [128 rows][64 k] f32 -> hi/lo bf16, swizzled ----
#pragma unroll
        for (int p = 0; p < 8; p++) {
            int rr = p * 16 + srow;
            int gk = k0 + skl;
            float4 v = make_float4(0.f, 0.f, 0.f, 0.f);
            if (gk < K) {
                v = *(const float4*)(A + (size_t)(bm + rr) * K + gk);
                if (BNA) {
                    v.x = fmaf(v.x, scale[gk + 0], shift[gk + 0]);
                    v.y = fmaf(v.y, scale[gk + 1], shift[gk + 1]);
                    v.z = fmaf(v.z, scale[gk + 2], shift[gk + 2]);
                    v.w = fmaf(v.w, scale[gk + 3], shift[gk + 3]);
                }
            }
            unsigned short h0 = f2bf(v.x), h1 = f2bf(v.y), h2 = f2bf(v.z), h3_ = f2bf(v.w);
            unsigned short l0 = f2bf(v.x - bf2f(h0)), l1 = f2bf(v.y - bf2f(h1));
            unsigned short l2 = f2bf(v.z - bf2f(h2)), l3 = f2bf(v.w - bf2f(h3_));
            int bo = rr * 128 + ((skl * 2) ^ (((rr >> 2) & 1) << 5));
            *(short4*)((char*)AhS + bo) = make_short4((short)h0, (short)h1, (short)h2, (short)h3_);
            *(short4*)((char*)AlS + bo) = make_short4((short)l0, (short)l1, (short)l2, (short)l3);
        }
        // ---- issue B fragment loads (global, weights are L2-hot) ----
        v8s Bfh[2][2], Bfl[2][2];
#pragma unroll
        for (int kc = 0; kc < 2; kc++)
#pragma unroll
            for (int nf = 0; nf < 2; nf++) {
                int col = bn + wn * 32 + nf * 16 + r16;
                size_t off = (size_t)col * Kpad + k0 + kc * 32 + q * 8;
                Bfh[kc][nf] = *(const v8s*)(const void*)(Bh + off);
                Bfl[kc][nf] = *(const v8s*)(const void*)(Bl + off);
            }
        __syncthreads();
        // ---- compute ----
#pragma unroll
        for (int kc = 0; kc < 2; kc++) {
#pragma unroll
            for (int mf = 0; mf < 4; mf++) {
                int arow = wm * 64 + mf * 16 + r16;
                int abo = arow * 128 + (((kc * 64) + q * 16) ^ (((arow >> 2) & 1) << 5));
                v8s ah = *(const v8s*)(const void*)((const char*)AhS + abo);
                v8s al = *(const v8s*)(const void*)((const char*)AlS + abo);
#pragma unroll
                for (int nf = 0; nf < 2; nf++) {
                    acc[mf][nf] = __builtin_amdgcn_mfma_f32_16x16x32_bf16(ah, Bfh[kc][nf], acc[mf][nf], 0, 0, 0);
                    acc[mf][nf] = __builtin_amdgcn_mfma_f32_16x16x32_bf16(al, Bfh[kc][nf], acc[mf][nf], 0, 0, 0);
                    acc[mf][nf] = __builtin_amdgcn_mfma_f32_16x16x32_bf16(ah, Bfl[kc][nf], acc[mf][nf], 0, 0, 0);
                }
            }
        }
        __syncthreads();
    }
    // ---- epilogue ----
#pragma unroll
    for (int mf = 0; mf < 4; mf++)
#pragma unroll
        for (int nf = 0; nf < 2; nf++) {
            int col = bn + wn * 32 + nf * 16 + r16;
            if (col < Ncol) {
                float bv = bias ? bias[col] : 0.f;
#pragma unroll
                for (int r = 0; r < 4; r++) {
                    int row = bm + wm * 64 + mf * 16 + q * 4 + r;
                    size_t o = (size_t)row * Ncol + col;
                    float v = acc[mf][nf][r] + bv;
                    if (ACCUM) v += C[o];
                    if (EPI == 1) v = fmaxf(v, 0.f);
                    if (EPI == 2) v = (v > 0.f) ? v : 0.01f * v;
                    C[o] = v;
                }
            }
        }
}

// ======================= weight prep: transpose + bf16 split =======================
// W [K,N] f32 -> Bh/Bl [Npad][Kpad] bf16, zero padded. fold_cin>0: PNA Wu fold
// (rows: [0,cin)=mean/8+s, [cin,2cin)=max, [2cin,3cin)=std from source [5cin,N]).
__global__ void prep_bt(const float* __restrict__ W, unsigned short* __restrict__ Bh,
                        unsigned short* __restrict__ Bl, int K, int N, int Kpad, int Npad,
                        int fold_cin)
{
    int idx = blockIdx.x * 256 + threadIdx.x;
    int total = Npad * Kpad;
    if (idx >= total) return;
    int n = idx / Kpad, k = idx % Kpad;
    float v = 0.f;
    if (n < N && k < K) {
        if (fold_cin == 0) v = W[(size_t)k * N + n];
        else {
            int cin = fold_cin;
            if (k < cin)          v = W[(size_t)(cin + k) * N + n] * 0.125f + W[(size_t)(3 * cin + k) * N + n];
            else if (k < 2 * cin) v = W[(size_t)(2 * cin + (k - cin)) * N + n];
            else                  v = W[(size_t)(4 * cin + (k - 2 * cin)) * N + n];
        }
    }
    unsigned short h = f2bf(v);
    Bh[idx] = h;
    Bl[idx] = f2bf(v - bf2f(h));
}

__global__ void prep_biasH(const float* __restrict__ bm, float* __restrict__ biasH, int cin)
{
    int i = blockIdx.x * 256 + threadIdx.x;
    if (i < 2 * cin) biasH[i] = (i < cin) ? 0.f : bm[i - cin];
}

// ======================= fp32 GEMM (small d2 path only) =======================
template<int EPI, bool ACCUM, bool BNA>
__global__ __launch_bounds__(256)
void gemm_k(const float* __restrict__ A, const float* __restrict__ Bw,
            float* __restrict__ C, int Ncol, int K,
            const float* __restrict__ bias,
            const float* __restrict__ scale, const float* __restrict__ shift)
{
    __shared__ float As[16][128];
    __shared__ float Bs[16][64];
    const int bm = blockIdx.y * 128;
    const int bn = blockIdx.x * 64;
    const int tid = threadIdx.x;
    const int tx = tid & 15, ty = tid >> 4;
    float acc[8][4];
#pragma unroll
    for (int i = 0; i < 8; i++)
#pragma unroll
        for (int j = 0; j < 4; j++) acc[i][j] = 0.f;

    for (int k0 = 0; k0 < K; k0 += 16) {
#pragma unroll
        for (int i = 0; i < 2; i++) {
            int idx = tid * 2 + i;
            int row = idx >> 2;
            int k4  = (idx & 3) << 2;
            const float* ap = A + (size_t)(bm + row) * K + k0 + k4;
            float4 v = *reinterpret_cast<const float4*>(ap);
            As[k4 + 0][row] = v.x;
            As[k4 + 1][row] = v.y;
            As[k4 + 2][row] = v.z;
            As[k4 + 3][row] = v.w;
        }
        {
            int row = tid >> 4;
            int c4  = (tid & 15) << 2;
            int gn  = bn + c4;
            float4 v;
            if (gn + 3 < Ncol) {
                v = *reinterpret_cast<const float4*>(Bw + (size_t)(k0 + row) * Ncol + gn);
            } else {
                float t0 = (gn + 0 < Ncol) ? Bw[(size_t)(k0 + row) * Ncol + gn + 0] : 0.f;
                float t1 = (gn + 1 < Ncol) ? Bw[(size_t)(k0 + row) * Ncol + gn + 1] : 0.f;
                float t2 = (gn + 2 < Ncol) ? Bw[(size_t)(k0 + row) * Ncol + gn + 2] : 0.f;
                float t3 = (gn + 3 < Ncol) ? Bw[(size_t)(k0 + row) * Ncol + gn + 3] : 0.f;
                v = make_float4(t0, t1, t2, t3);
            }
            *reinterpret_cast<float4*>(&Bs[row][c4]) = v;
        }
        __syncthreads();
#pragma unroll
        for (int kk = 0; kk < 16; kk++) {
            float a0[8], b0[4];
#pragma unroll
            for (int i = 0; i < 8; i++) a0[i] = As[kk][ty * 8 + i];
#pragma unroll
            for (int j = 0; j < 4; j++) b0[j] = Bs[kk][tx * 4 + j];
#pragma unroll
            for (int i = 0; i < 8; i++)
#pragma unroll
                for (int j = 0; j < 4; j++) acc[i][j] = fmaf(a0[i], b0[j], acc[i][j]);
        }
        __syncthreads();
    }
#pragma unroll
    for (int i = 0; i < 8; i++) {
        int r = bm + ty * 8 + i;
#pragma unroll
        for (int j = 0; j < 4; j++) {
            int c = bn + tx * 4 + j;
            if (c < Ncol) {
                float v = acc[i][j];
                if (bias) v += bias[c];
                size_t off = (size_t)r * Ncol + c;
                if (ACCUM) v += C[off];
                if (EPI == 1) v = fmaxf(v, 0.f);
                if (EPI == 2) v = (v > 0.f) ? v : 0.01f * v;
                C[off] = v;
            }
        }
    }
}

// ======================= PNA aggregation v2 =======================
// Grid (64 groups, ceil(cin/64) chunks, 4 node-quarters). Block 256 = 4 waves x 64 lanes.
// lane = channel (Wme column cached in 16 registers), wave = node sub-lane.
// msg = H2[src][c] + H2[v][cin+c] + dot16(es_e, Wme[:,c]); agg = [sum|max|std].
__global__ __launch_bounds__(256)
void agg2_k(const float* __restrict__ H2, const float* __restrict__ es,
            const int* __restrict__ src, const float* __restrict__ Wme,
            float* __restrict__ agg, int cin, int ldH)
{
    const int g = blockIdx.x;
    const int c0 = blockIdx.y * 64;
    const int qz = blockIdx.z;
    const int tid = threadIdx.x;
    const int nl = tid >> 6, c = tid & 63;
    const int cc = c0 + c;
    const bool act = cc < cin;
    __shared__ float esl[4][128];
    __shared__ int srcl[512];
    {
        int e0 = g * 2048 + qz * 512;
        for (int i = tid; i < 512; i += 256) srcl[i] = src[e0 + i] - g * 256;
    }
    float wreg[16];
#pragma unroll
    for (int j = 0; j < 16; j++) wreg[j] = act ? Wme[j * cin + cc] : 0.f;
    __syncthreads();
    const float* Hsrc = H2 + (size_t)(g * 256) * ldH + c0;
    const float* Hdst = H2 + (size_t)(g * 256) * ldH + cin + c0;
    for (int i = 0; i < 16; i++) {
        const int vl = qz * 64 + i * 4 + nl;
        {
            const float* ep = es + (size_t)(g * 256 + vl) * 128;
            esl[nl][c] = ep[c];
            esl[nl][64 + c] = ep[64 + c];
        }
        __syncthreads();
        if (act) {
            float hd = Hdst[(size_t)vl * ldH + c];
            float sum = 0.f, sq = 0.f, mx = -INFINITY;
#pragma unroll
            for (int e = 0; e < 8; e++) {
                int sl = srcl[(i * 4 + nl) * 8 + e];
                float m = hd + Hsrc[(size_t)sl * ldH + c];
                float4 e0 = *(const float4*)&esl[nl][e * 16 + 0];
                float4 e1 = *(const float4*)&esl[nl][e * 16 + 4];
                float4 e2 = *(const float4*)&esl[nl][e * 16 + 8];
                float4 e3 = *(const float4*)&esl[nl][e * 16 + 12];
                m = fmaf(e0.x, wreg[0], m);  m = fmaf(e0.y, wreg[1], m);
                m = fmaf(e0.z, wreg[2], m);  m = fmaf(e0.w, wreg[3], m);
                m = fmaf(e1.x, wreg[4], m);  m = fmaf(e1.y, wreg[5], m);
                m = fmaf(e1.z, wreg[6], m);  m = fmaf(e1.w, wreg[7], m);
                m = fmaf(e2.x, wreg[8], m);  m = fmaf(e2.y, wreg[9], m);
                m = fmaf(e2.z, wreg[10], m); m = fmaf(e2.w, wreg[11], m);
                m = fmaf(e3.x, wreg[12], m); m = fmaf(e3.y, wreg[13], m);
                m = fmaf(e3.z, wreg[14], m); m = fmaf(e3.w, wreg[15], m);
                sum += m;
                sq = fmaf(m, m, sq);
                mx = fmaxf(mx, m);
            }
            float mean = sum * 0.125f, msq = sq * 0.125f;
            float stdv = sqrtf(fmaxf(msq - mean * mean, 0.f) + 1e-30f);
            size_t o = (size_t)(g * 256 + vl) * 3 * cin + cc;
            agg[o] = sum;
            agg[o + cin] = mx;
            agg[o + 2 * cin] = stdv;
        }
        __syncthreads();
    }
}

// ======================= BatchNorm stats (deterministic 2-stage) =======================
__global__ void bnstats1_k(const float* __restrict__ u, float* __restrict__ part, int cout)
{
    int c = threadIdx.x;
    if (c >= cout) return;
    int r0 = blockIdx.x * 256;
    float s = 0.f, q = 0.f;
    for (int r = r0; r < r0 + 256; r++) {
        float v = u[(size_t)r * cout + c];
        s += v;
        q = fmaf(v, v, q);
    }
    part[(size_t)blockIdx.x * cout + c] = s;
    part[(size_t)(64 + blockIdx.x) * cout + c] = q;
}

__global__ void bnstats2_k(const float* __restrict__ part, const float* __restrict__ bng,
                           const float* __restrict__ bnb, float* __restrict__ scale,
                           float* __restrict__ shift, int cout)
{
    int c = threadIdx.x;
    if (c >= cout) return;
    float s = 0.f, q = 0.f;
    for (int b = 0; b < 64; b++) { s += part[(size_t)b * cout + c]; q += part[(size_t)(64 + b) * cout + c]; }
    float mean = s / 16384.f;
    float var  = q / 16384.f - mean * mean;
    float sc   = bng[c] / sqrtf(var + 1e-5f);
    scale[c] = sc;
    shift[c] = bnb[c] - mean * sc;
}

// ======================= head =======================
__global__ void rowmax_k(const float* __restrict__ h3, float* __restrict__ nm)
{
    int wave = threadIdx.x >> 6;
    int lane = threadIdx.x & 63;
    int node = blockIdx.x * 4 + wave;
    const float* row = h3 + (size_t)node * 192;
    float m = -INFINITY;
    for (int t = lane; t < 192; t += 64) m = fmaxf(m, row[t]);
#pragma unroll
    for (int off = 32; off > 0; off >>= 1) m = fmaxf(m, __shfl_down(m, off, 64));
    if (lane == 0) nm[node] = m;
}

__global__ __launch_bounds__(256) void g_k(const float* __restrict__ nm,
    const float* __restrict__ W3, const float* __restrict__ b3,
    const float* __restrict__ W4, const float* __restrict__ b4,
    float* __restrict__ g)
{
    __shared__ float row[256];
    __shared__ float t1[64];
    int b = blockIdx.x, tid = threadIdx.x;
    row[tid] = nm[b * 256 + tid];
    __syncthreads();
    if (tid < 64) {
        float a = b3[tid];
        for (int k = 0; k < 256; k++) a = fmaf(row[k], W3[k * 64 + tid], a);
        t1[tid] = fmaxf(a, 0.f);
    }
    __syncthreads();
    float a = b4[tid];
    for (int j = 0; j < 64; j++) a = fmaf(t1[j], W4[j * 256 + tid], a);
    g[b * 256 + tid] = 1.f / (1.f + expf(-a));
}

// ======================= masked softmax (parallel, 2-pass) =======================
__global__ __launch_bounds__(256) void sm1_k(const float* __restrict__ mask,
    const float* __restrict__ g, const float* __restrict__ h3, float* __restrict__ part)
{
    int b = blockIdx.x, s = blockIdx.y, tid = threadIdx.x;
    float l[24];
#pragma unroll
    for (int t = 0; t < 24; t++) {
        int i = s * 6144 + t * 256 + tid;
        size_t idx = (size_t)b * 49152 + i;
        float mk = mask[idx];
        l[t] = (mk == 0.f) ? -1e5f : g[b * 256 + i / 192] * h3[idx];
    }
    float m = -INFINITY;
#pragma unroll
    for (int t = 0; t < 24; t++) m = fmaxf(m, l[t]);
    __shared__ float red[256];
    red[tid] = m; __syncthreads();
    for (int st = 128; st > 0; st >>= 1) { if (tid < st) red[tid] = fmaxf(red[tid], red[tid + st]); __syncthreads(); }
    m = red[0]; __syncthreads();
    float z = 0.f;
#pragma unroll
    for (int t = 0; t < 24; t++) z += expf(l[t] - m);
    red[tid] = z; __syncthreads();
    for (int st = 128; st > 0; st >>= 1) { if (tid < st) red[tid] += red[tid + st]; __syncthreads(); }
    if (tid == 0) { part[(b * 8 + s) * 2] = m; part[(b * 8 + s) * 2 + 1] = red[0]; }
}

__global__ void sm2_k(const float* __restrict__ part, float* __restrict__ mz)
{
    int b = threadIdx.x;
    if (b >= 64) return;
    float M = -INFINITY;
    for (int s = 0; s < 8; s++) M = fmaxf(M, part[(b * 8 + s) * 2]);
    float Z = 0.f;
    for (int s = 0; s < 8; s++) Z += part[(b * 8 + s) * 2 + 1] * expf(part[(b * 8 + s) * 2] - M);
    mz[b * 2] = M;
    mz[b * 2 + 1] = 1.f / Z;
}

__global__ __launch_bounds__(256) void sm3_k(const float* __restrict__ mask,
    const float* __restrict__ g, const float* __restrict__ h3,
    const float* __restrict__ mz, float* __restrict__ out)
{
    int b = blockIdx.x, s = blockIdx.y, tid = threadIdx.x;
    float M = mz[b * 2], invZ = mz[b * 2 + 1];
#pragma unroll
    for (int t = 0; t < 24; t++) {
        int i = s * 6144 + t * 256 + tid;
        size_t idx = (size_t)b * 49152 + i;
        float mk = mask[idx];
        float v = (mk == 0.f) ? -1e5f : g[b * 256 + i / 192] * h3[idx];
        out[idx] = expf(v - M) * invZ;
    }
}

// ======================= launcher =======================
extern "C" void kernel_launch(void* const* d_in, const int* in_sizes, int n_in,
                              void* d_out, int out_size, void* d_ws, size_t ws_size,
                              hipStream_t stream)
{
    const float* ns   = (const float*)d_in[0];
    const float* es   = (const float*)d_in[1];
    const float* dm   = (const float*)d_in[2];
    const float* mask = (const float*)d_in[3];
    const int*   src  = (const int*)d_in[4];
    const float* Wm1 = (const float*)d_in[6],  *bm1 = (const float*)d_in[7];
    const float* Wu1 = (const float*)d_in[8],  *bu1 = (const float*)d_in[9];
    const float* bng1= (const float*)d_in[10], *bnb1= (const float*)d_in[11];
    const float* Wx1 = (const float*)d_in[12], *bx1 = (const float*)d_in[13];
    const float* Wm2 = (const float*)d_in[14], *bm2 = (const float*)d_in[15];
    const float* Wu2 = (const float*)d_in[16], *bu2 = (const float*)d_in[17];
    const float* bng2= (const float*)d_in[18], *bnb2= (const float*)d_in[19];
    const float* Wx2 = (const float*)d_in[20], *bx2 = (const float*)d_in[21];
    const float* Wm3 = (const float*)d_in[22], *bm3 = (const float*)d_in[23];
    const float* Wu3 = (const float*)d_in[24], *bu3 = (const float*)d_in[25];
    const float* bng3= (const float*)d_in[26], *bnb3= (const float*)d_in[27];
    const float* Wx3 = (const float*)d_in[28], *bx3 = (const float*)d_in[29];
    const float* W1 = (const float*)d_in[30], *b1 = (const float*)d_in[31];
    const float* W2 = (const float*)d_in[32], *b2 = (const float*)d_in[33];
    const float* W3 = (const float*)d_in[34], *b3 = (const float*)d_in[35];
    const float* W4 = (const float*)d_in[36], *b4 = (const float*)d_in[37];
    float* out = (float*)d_out;

    const int N = NNODE;
    char* base = (char*)d_ws;
    size_t off = 0;
    auto alloc = [&](size_t bytes) -> void* {
        void* p = base + off;
        off = (off + bytes + 255) & ~(size_t)255;
        return p;
    };
    float* H2   = (float*)alloc((size_t)N * 832 * 4);
    float* agg  = (float*)alloc((size_t)N * 1248 * 4);
    float* u    = (float*)alloc((size_t)N * 384 * 4);
    float* hA   = (float*)alloc((size_t)N * 384 * 4);
    float* h3b  = (float*)alloc((size_t)N * 192 * 4);
    float* d2   = (float*)alloc((size_t)N * 32 * 4);
    float* part = (float*)alloc((size_t)128 * 384 * 4);
    float* scale= (float*)alloc(384 * 4);
    float* shift= (float*)alloc(384 * 4);
    float* nm   = (float*)alloc((size_t)N * 4);
    float* gbuf = (float*)alloc((size_t)N * 4);
    float* smp  = (float*)alloc(64 * 8 * 2 * 4);
    float* smz  = (float*)alloc(64 * 2 * 4);
    float* biasH1 = (float*)alloc(256 * 4);
    float* biasH2 = (float*)alloc(832 * 4);
    float* biasH3 = (float*)alloc(768 * 4);
    auto aw = [&](size_t elems) -> unsigned short* { return (unsigned short*)alloc(elems * 2); };
    unsigned short *Wm1tH = aw(256 * 128),   *Wm1tL = aw(256 * 128);
    unsigned short *Wu1hH = aw(384 * 128),   *Wu1hL = aw(384 * 128);
    unsigned short *WuA1H = aw(384 * 384),   *WuA1L = aw(384 * 384);
    unsigned short *Wx1tH = aw(384 * 384),   *Wx1tL = aw(384 * 384);
    unsigned short *Wm2tH = aw(832 * 448),   *Wm2tL = aw(832 * 448);
    unsigned short *Wu2hH = aw(384 * 448),   *Wu2hL = aw(384 * 448);
    unsigned short *WuA2H = aw(384 * 1280),  *WuA2L = aw(384 * 1280);
    unsigned short *Wx2tH = aw(384 * 384),   *Wx2tL = aw(384 * 384);
    unsigned short *Wm3tH = aw(768 * 384),   *Wm3tL = aw(768 * 384);
    unsigned short *Wu3hH = aw(192 * 384),   *Wu3hL = aw(192 * 384);
    unsigned short *WuA3H = aw(192 * 1152),  *WuA3L = aw(192 * 1152);
    unsigned short *Wx3tH = aw(192 * 192),   *Wx3tL = aw(192 * 192);
    float* d2t = H2;  // alias: dead before H2 first written

    auto gp = [](int n) { return dim3((n + 255) / 256); };
    // ---- weight prep ----
    prep_bt<<<gp(128 * 128), 256, 0, stream>>>(Wm1,             Wm1tH,             Wm1tL,             128, 128, 128, 128, 0);
    prep_bt<<<gp(128 * 128), 256, 0, stream>>>(Wm1 + 128 * 128, Wm1tH + 128 * 128, Wm1tL + 128 * 128, 128, 128, 128, 128, 0);
    prep_bt<<<gp(384 * 128), 256, 0, stream>>>(Wu1, Wu1hH, Wu1hL, 128, 384, 128, 384, 0);
    prep_bt<<<gp(384 * 384), 256, 0, stream>>>(Wu1, WuA1H, WuA1L, 384, 384, 384, 384, 128);
    prep_bt<<<gp(384 * 384), 256, 0, stream>>>(Wx1, Wx1tH, Wx1tL, 384, 384, 384, 384, 0);
    prep_bt<<<gp(416 * 448), 256, 0, stream>>>(Wm2,             Wm2tH,             Wm2tL,             416, 416, 448, 416, 0);
    prep_bt<<<gp(416 * 448), 256, 0, stream>>>(Wm2 + 416 * 416, Wm2tH + 416 * 448, Wm2tL + 416 * 448, 416, 416, 448, 416, 0);
    prep_bt<<<gp(384 * 448), 256, 0, stream>>>(Wu2, Wu2hH, Wu2hL, 416, 384, 448, 384, 0);
    prep_bt<<<gp(384 * 1280), 256, 0, stream>>>(Wu2, WuA2H, WuA2L, 1248, 384, 1280, 384, 416);
    prep_bt<<<gp(384 * 384), 256, 0, stream>>>(Wx2, Wx2tH, Wx2tL, 384, 384, 384, 384, 0);
    prep_bt<<<gp(384 * 384), 256, 0, stream>>>(Wm3,             Wm3tH,             Wm3tL,             384, 384, 384, 384, 0);
    prep_bt<<<gp(384 * 384), 256, 0, stream>>>(Wm3 + 384 * 384, Wm3tH + 384 * 384, Wm3tL + 384 * 384, 384, 384, 384, 384, 0);
    prep_bt<<<gp(192 * 384), 256, 0, stream>>>(Wu3, Wu3hH, Wu3hL, 384, 192, 384, 192, 0);
    prep_bt<<<gp(192 * 1152), 256, 0, stream>>>(Wu3, WuA3H, WuA3L, 1152, 192, 1152, 192, 384);
    prep_bt<<<gp(192 * 192), 256, 0, stream>>>(Wx3, Wx3tH, Wx3tL, 192, 192, 192, 192, 0);
    prep_biasH<<<gp(256), 256, 0, stream>>>(bm1, biasH1, 128);
    prep_biasH<<<gp(832), 256, 0, stream>>>(bm2, biasH2, 416);
    prep_biasH<<<gp(768), 256, 0, stream>>>(bm3, biasH3, 384);

    // ---- d2 = (dm@W1+b1)@W2+b2 (small fp32 path) ----
    gemm_k<0, false, false><<<dim3(1, 128), 256, 0, stream>>>(dm, W1, d2t, 64, 256, b1, nullptr, nullptr);
    gemm_k<0, false, false><<<dim3(1, 128), 256, 0, stream>>>(d2t, W2, d2, 32, 64, b2, nullptr, nullptr);

    // ---- layer 1: h=ns, cin=128, cout=384 ----
    mgemm<0, false, false><<<dim3(4, 128), 256, 0, stream>>>(ns, Wm1tH, Wm1tL, H2, 256, 128, 128, biasH1, nullptr, nullptr);
    agg2_k<<<dim3(64, 2, 4), 256, 0, stream>>>(H2, es, src, Wm1 + 2 * 128 * 128, agg, 128, 256);
    mgemm<0, false, false><<<dim3(6, 128), 256, 0, stream>>>(ns, Wu1hH, Wu1hL, u, 384, 128, 128, bu1, nullptr, nullptr);
    mgemm<0, true, false><<<dim3(6, 128), 256, 0, stream>>>(agg, WuA1H, WuA1L, u, 384, 384, 384, nullptr, nullptr, nullptr);
    bnstats1_k<<<64, 384, 0, stream>>>(u, part, 384);
    bnstats2_k<<<1, 384, 0, stream>>>(part, bng1, bnb1, scale, shift, 384);
    mgemm<1, false, true><<<dim3(6, 128), 256, 0, stream>>>(u, Wx1tH, Wx1tL, hA, 384, 384, 384, bx1, scale, shift);

    // ---- layer 2: h=[hA|d2] (K-split), cin=416, cout=384 ----
    mgemm<0, false, false><<<dim3(13, 128), 256, 0, stream>>>(hA, Wm2tH, Wm2tL, H2, 832, 384, 448, biasH2, nullptr, nullptr);
    mgemm<0, true, false><<<dim3(13, 128), 256, 0, stream>>>(d2, Wm2tH + 384, Wm2tL + 384, H2, 832, 32, 448, nullptr, nullptr, nullptr);
    agg2_k<<<dim3(64, 7, 4), 256, 0, stream>>>(H2, es, src, Wm2 + 2 * 416 * 416, agg, 416, 832);
    mgemm<0, false, false><<<dim3(6, 128), 256, 0, stream>>>(hA, Wu2hH, Wu2hL, u, 384, 384, 448, bu2, nullptr, nullptr);
    mgemm<0, true, false><<<dim3(6, 128), 256, 0, stream>>>(d2, Wu2hH + 384, Wu2hL + 384, u, 384, 32, 448, nullptr, nullptr, nullptr);
    mgemm<0, true, false><<<dim3(6, 128), 256, 0, stream>>>(agg, WuA2H, WuA2L, u, 384, 1248, 1280, nullptr, nullptr, nullptr);
    bnstats1_k<<<64, 384, 0, stream>>>(u, part, 384);
    bnstats2_k<<<1, 384, 0, stream>>>(part, bng2, bnb2, scale, shift, 384);
    mgemm<1, false, true><<<dim3(6, 128), 256, 0, stream>>>(u, Wx2tH, Wx2tL, hA, 384, 384, 384, bx2, scale, shift);

    // ---- layer 3: h=hA(h2), cin=384, cout=192 ----
    mgemm<0, false, false><<<dim3(12, 128), 256, 0, stream>>>(hA, Wm3tH, Wm3tL, H2, 768, 384, 384, biasH3, nullptr, nullptr);
    agg2_k<<<dim3(64, 6, 4), 256, 0, stream>>>(H2, es, src, Wm3 + 2 * 384 * 384, agg, 384, 768);
    mgemm<0, false, false><<<dim3(3, 128), 256, 0, stream>>>(hA, Wu3hH, Wu3hL, u, 192, 384, 384, bu3, nullptr, nullptr);
    mgemm<0, true, false><<<dim3(3, 128), 256, 0, stream>>>(agg, WuA3H, WuA3L, u, 192, 1152, 1152, nullptr, nullptr, nullptr);
    bnstats1_k<<<64, 384, 0, stream>>>(u, part, 192);
    bnstats2_k<<<1, 384, 0, stream>>>(part, bng3, bnb3, scale, shift, 192);
    mgemm<2, false, true><<<dim3(3, 128), 256, 0, stream>>>(u, Wx3tH, Wx3tL, h3b, 192, 192, 192, bx3, scale, shift);

    // ---- head ----
    rowmax_k<<<N / 4, 256, 0, stream>>>(h3b, nm);
    g_k<<<64, 256, 0, stream>>>(nm, W3, b3, W4, b4, gbuf);
    sm1_k<<<dim3(64, 8), 256, 0, stream>>>(mask, gbuf, h3b, smp);
    sm2_k<<<1, 64, 0, stream>>>(smp, smz);
    sm3_k<<<dim3(64, 8), 256, 0, stream>>>(mask, gbuf, h3b, smz, out);
}

// Round 3
// 816.993 us; speedup vs baseline: 2.6710x; 1.3433x over previous
//
#include <hip/hip_runtime.h>
#include <hip/hip_bf16.h>

#define NNODE 16384

typedef short v8s __attribute__((ext_vector_type(8)));
typedef float v4f __attribute__((ext_vector_type(4)));
typedef unsigned short ushort_t;

__device__ __forceinline__ unsigned short f2bf(float v) {
    unsigned u = __float_as_uint(v);
    unsigned r = (u + 0x7FFF + ((u >> 16) & 1)) >> 16;
    return (unsigned short)r;
}
__device__ __forceinline__ float bf2f(unsigned short s) {
    return __uint_as_float(((unsigned)s) << 16);
}

// ======================= split-bf16 MFMA GEMM v2 =======================
// C[16384, Ncol] = epi( A @ B + bias ). A pre-split bf16 planes [16384][ldA] (valid K cols).
// B pre-split/transposed [Npad][Kpad]. Tile 128x128, 4 waves (2x2), wave tile 64x64.
// A+B staged in LDS with (row&7)<<4 XOR swizzle. 3-term split product.
// OUT: 0 = f32 C, 1 = split bf16 planes Ch/Cl.
template<int EPI, int OUT>
__global__ __launch_bounds__(256, 2)
void mgemm2(const unsigned short* __restrict__ Ah, const unsigned short* __restrict__ Al,
            int ldA, int K,
            const unsigned short* __restrict__ Bh, const unsigned short* __restrict__ Bl,
            int Kpad,
            float* __restrict__ Cf, unsigned short* __restrict__ Ch, unsigned short* __restrict__ Cl,
            int ldC, int Ncol, const float* __restrict__ bias)
{
    __shared__ __align__(16) unsigned short AhS[128 * 64];
    __shared__ __align__(16) unsigned short AlS[128 * 64];
    __shared__ __align__(16) unsigned short BhS[128 * 64];
    __shared__ __align__(16) unsigned short BlS[128 * 64];
    const int bm = blockIdx.x * 128;   // rows in x: col-blocks of a row-panel share an XCD L2
    const int bn = blockIdx.y * 128;
    const int tid = threadIdx.x;
    const int lane = tid & 63, wid = tid >> 6;
    const int wm = wid >> 1, wn = wid & 1;
    const int r16 = lane & 15, q = lane >> 4;
    v4f acc[4][4];
#pragma unroll
    for (int i = 0; i < 4; i++)
#pragma unroll
        for (int j = 0; j < 4; j++) acc[i][j] = (v4f){0.f, 0.f, 0.f, 0.f};

    const int nK = (K + 63) >> 6;
    for (int s = 0; s < nK; s++) {
        const int k0 = s << 6;
        // ---- stage A,B tiles: 128 rows x 64 k bf16 x 2 planes each ----
#pragma unroll
        for (int p = 0; p < 4; p++) {
            int chunk = p * 256 + tid;          // 0..1023
            int row = chunk >> 3;               // 0..127
            int o16 = (chunk & 7) << 4;         // byte offset within 128B row
            int gk = k0 + (o16 >> 1);           // element offset
            v8s hv = (v8s){0,0,0,0,0,0,0,0};
            v8s lv = (v8s){0,0,0,0,0,0,0,0};
            if (gk < K) {
                size_t go = (size_t)(bm + row) * ldA + gk;
                hv = *(const v8s*)(const void*)(Ah + go);
                lv = *(const v8s*)(const void*)(Al + go);
            }
            int bo = row * 128 + (o16 ^ ((row & 7) << 4));
            *(v8s*)(void*)((char*)AhS + bo) = hv;
            *(v8s*)(void*)((char*)AlS + bo) = lv;
            size_t gb = (size_t)(bn + row) * Kpad + gk;   // B zero-padded to Kpad
            v8s bhv = *(const v8s*)(const void*)(Bh + gb);
            v8s blv = *(const v8s*)(const void*)(Bl + gb);
            *(v8s*)(void*)((char*)BhS + bo) = bhv;
            *(v8s*)(void*)((char*)BlS + bo) = blv;
        }
        __syncthreads();
        // ---- compute ----
#pragma unroll
        for (int kc = 0; kc < 2; kc++) {
            v8s bh[4], bl[4];
#pragma unroll
            for (int nf = 0; nf < 4; nf++) {
                int bcol = wn * 64 + nf * 16 + r16;
                int bo = bcol * 128 + (((kc * 64) + q * 16) ^ ((bcol & 7) << 4));
                bh[nf] = *(const v8s*)(const void*)((const char*)BhS + bo);
                bl[nf] = *(const v8s*)(const void*)((const char*)BlS + bo);
            }
#pragma unroll
            for (int mf = 0; mf < 4; mf++) {
                int arow = wm * 64 + mf * 16 + r16;
                int ao = arow * 128 + (((kc * 64) + q * 16) ^ ((arow & 7) << 4));
                v8s ah = *(const v8s*)(const void*)((const char*)AhS + ao);
                v8s al = *(const v8s*)(const void*)((const char*)AlS + ao);
#pragma unroll
                for (int nf = 0; nf < 4; nf++) {
                    acc[mf][nf] = __builtin_amdgcn_mfma_f32_16x16x32_bf16(ah, bh[nf], acc[mf][nf], 0, 0, 0);
                    acc[mf][nf] = __builtin_amdgcn_mfma_f32_16x16x32_bf16(al, bh[nf], acc[mf][nf], 0, 0, 0);
                    acc[mf][nf] = __builtin_amdgcn_mfma_f32_16x16x32_bf16(ah, bl[nf], acc[mf][nf], 0, 0, 0);
                }
            }
        }
        __syncthreads();
    }
    // ---- epilogue ----
#pragma unroll
    for (int mf = 0; mf < 4; mf++)
#pragma unroll
        for (int nf = 0; nf < 4; nf++) {
            int col = bn + wn * 64 + nf * 16 + r16;
            if (col < Ncol) {
                float bv = bias ? bias[col] : 0.f;
#pragma unroll
                for (int r = 0; r < 4; r++) {
                    int row = bm + wm * 64 + mf * 16 + q * 4 + r;
                    float v = acc[mf][nf][r] + bv;
                    if (EPI == 1) v = fmaxf(v, 0.f);
                    if (EPI == 2) v = (v > 0.f) ? v : 0.01f * v;
                    size_t o = (size_t)row * ldC + col;
                    if (OUT == 0) {
                        Cf[o] = v;
                    } else {
                        unsigned short h = f2bf(v);
                        Ch[o] = h;
                        Cl[o] = f2bf(v - bf2f(h));
                    }
                }
            }
        }
}

// ======================= weight preps =======================
// plain transpose+split: B[n][k] = (n<N && k<K) ? W[k,N]=W[k*N+n] : 0
__global__ void prep_bt(const float* __restrict__ W, unsigned short* __restrict__ Bh,
                        unsigned short* __restrict__ Bl, int K, int N, int Kpad, int Npad)
{
    int idx = blockIdx.x * 256 + threadIdx.x;
    if (idx >= Npad * Kpad) return;
    int n = idx / Kpad, k = idx % Kpad;
    float v = (n < N && k < K) ? W[(size_t)k * N + n] : 0.f;
    unsigned short h = f2bf(v);
    Bh[idx] = h;
    Bl[idx] = f2bf(v - bf2f(h));
}

// Wu fold: source [5cin, cout]; X row layout [h(cin) | sum | max | std] -> K = 4cin
__global__ void prep_wu(const float* __restrict__ Wu, unsigned short* __restrict__ Bh,
                        unsigned short* __restrict__ Bl, int cin, int cout, int Npad)
{
    int Kpad = 4 * cin;
    int idx = blockIdx.x * 256 + threadIdx.x;
    if (idx >= Npad * Kpad) return;
    int n = idx / Kpad, k = idx % Kpad;
    float v = 0.f;
    if (n < cout) {
        int qq = k / cin, r = k - qq * cin;
        if (qq == 0)      v = Wu[(size_t)r * cout + n];
        else if (qq == 1) v = Wu[(size_t)(cin + r) * cout + n] * 0.125f + Wu[(size_t)(3 * cin + r) * cout + n];
        else if (qq == 2) v = Wu[(size_t)(2 * cin + r) * cout + n];
        else              v = Wu[(size_t)(4 * cin + r) * cout + n];
    }
    unsigned short h = f2bf(v);
    Bh[idx] = h;
    Bl[idx] = f2bf(v - bf2f(h));
}

// Wx scaled by BN scale: B[n][k] = Wx[k][n]*scale[k]
__global__ void prep_wx(const float* __restrict__ Wx, const float* __restrict__ scale,
                        unsigned short* __restrict__ Bh, unsigned short* __restrict__ Bl,
                        int K, int N, int Kpad, int Npad)
{
    int idx = blockIdx.x * 256 + threadIdx.x;
    if (idx >= Npad * Kpad) return;
    int n = idx / Kpad, k = idx % Kpad;
    float v = (n < N && k < K) ? Wx[(size_t)k * N + n] * scale[k] : 0.f;
    unsigned short h = f2bf(v);
    Bh[idx] = h;
    Bl[idx] = f2bf(v - bf2f(h));
}

// bias2[n] = bx[n] + sum_k shift[k]*Wx[k][n]
__global__ void bias2_k(const float* __restrict__ Wx, const float* __restrict__ bx,
                        const float* __restrict__ shift, float* __restrict__ bias2,
                        int K, int N)
{
    int n = blockIdx.x * 256 + threadIdx.x;
    if (n >= N) return;
    float s = bx[n];
    for (int k = 0; k < K; k++) s = fmaf(shift[k], Wx[(size_t)k * N + n], s);
    bias2[n] = s;
}

// Wm bias for H2 columns: [0]*cin ++ bm
__global__ void prep_biasH(const float* __restrict__ bm, float* __restrict__ biasH, int cin)
{
    int i = blockIdx.x * 256 + threadIdx.x;
    if (i < 2 * cin) biasH[i] = (i < cin) ? 0.f : bm[i - cin];
}

// f32 [16384, w] (ld ldS) -> split planes at column offset offX
__global__ void csplit_k(const float* __restrict__ src, int ldS, int w,
                         unsigned short* __restrict__ Xh, unsigned short* __restrict__ Xl,
                         int ldX, int offX)
{
    int idx = blockIdx.x * 256 + threadIdx.x;
    if (idx >= NNODE * w) return;
    int rrow = idx / w, c = idx - rrow * w;
    float v = src[(size_t)rrow * ldS + c];
    unsigned short h = f2bf(v);
    size_t o = (size_t)rrow * ldX + offX + c;
    Xh[o] = h;
    Xl[o] = f2bf(v - bf2f(h));
}

// ======================= fp32 GEMM (small d2 path) =======================
__global__ __launch_bounds__(256)
void gemm_k(const float* __restrict__ A, const float* __restrict__ Bw,
            float* __restrict__ C, int Ncol, int K, const float* __restrict__ bias)
{
    __shared__ float As[16][128];
    __shared__ float Bs[16][64];
    const int bm = blockIdx.y * 128;
    const int bn = blockIdx.x * 64;
    const int tid = threadIdx.x;
    const int tx = tid & 15, ty = tid >> 4;
    float acc[8][4];
#pragma unroll
    for (int i = 0; i < 8; i++)
#pragma unroll
        for (int j = 0; j < 4; j++) acc[i][j] = 0.f;

    for (int k0 = 0; k0 < K; k0 += 16) {
#pragma unroll
        for (int i = 0; i < 2; i++) {
            int idx = tid * 2 + i;
            int row = idx >> 2;
            int k4  = (idx & 3) << 2;
            const float* ap = A + (size_t)(bm + row) * K + k0 + k4;
            float4 v = *reinterpret_cast<const float4*>(ap);
            As[k4 + 0][row] = v.x;
            As[k4 + 1][row] = v.y;
            As[k4 + 2][row] = v.z;
            As[k4 + 3][row] = v.w;
        }
        {
            int row = tid >> 4;
            int c4  = (tid & 15) << 2;
            int gn  = bn + c4;
            float4 v;
            if (gn + 3 < Ncol) {
                v = *reinterpret_cast<const float4*>(Bw + (size_t)(k0 + row) * Ncol + gn);
            } else {
                float t0 = (gn + 0 < Ncol) ? Bw[(size_t)(k0 + row) * Ncol + gn + 0] : 0.f;
                float t1 = (gn + 1 < Ncol) ? Bw[(size_t)(k0 + row) * Ncol + gn + 1] : 0.f;
                float t2 = (gn + 2 < Ncol) ? Bw[(size_t)(k0 + row) * Ncol + gn + 2] : 0.f;
                float t3 = (gn + 3 < Ncol) ? Bw[(size_t)(k0 + row) * Ncol + gn + 3] : 0.f;
                v = make_float4(t0, t1, t2, t3);
            }
            *reinterpret_cast<float4*>(&Bs[row][c4]) = v;
        }
        __syncthreads();
#pragma unroll
        for (int kk = 0; kk < 16; kk++) {
            float a0[8], b0[4];
#pragma unroll
            for (int i = 0; i < 8; i++) a0[i] = As[kk][ty * 8 + i];
#pragma unroll
            for (int j = 0; j < 4; j++) b0[j] = Bs[kk][tx * 4 + j];
#pragma unroll
            for (int i = 0; i < 8; i++)
#pragma unroll
                for (int j = 0; j < 4; j++) acc[i][j] = fmaf(a0[i], b0[j], acc[i][j]);
        }
        __syncthreads();
    }
#pragma unroll
    for (int i = 0; i < 8; i++) {
        int r = bm + ty * 8 + i;
#pragma unroll
        for (int j = 0; j < 4; j++) {
            int c = bn + tx * 4 + j;
            if (c < Ncol) C[(size_t)r * Ncol + c] = acc[i][j] + (bias ? bias[c] : 0.f);
        }
    }
}

// ======================= PNA aggregation (split-bf16 output into X) =======================
__global__ __launch_bounds__(256)
void agg2_k(const float* __restrict__ H2, const float* __restrict__ es,
            const int* __restrict__ src, const float* __restrict__ Wme,
            unsigned short* __restrict__ Xh, unsigned short* __restrict__ Xl,
            int cin, int ldH, int ldX, int offX)
{
    const int g = blockIdx.x;
    const int c0 = blockIdx.y * 64;
    const int qz = blockIdx.z;
    const int tid = threadIdx.x;
    const int nl = tid >> 6, c = tid & 63;
    const int cc = c0 + c;
    const bool act = cc < cin;
    __shared__ float esl[4][128];
    __shared__ int srcl[512];
    {
        int e0 = g * 2048 + qz * 512;
        for (int i = tid; i < 512; i += 256) srcl[i] = src[e0 + i] - g * 256;
    }
    float wreg[16];
#pragma unroll
    for (int j = 0; j < 16; j++) wreg[j] = act ? Wme[j * cin + cc] : 0.f;
    __syncthreads();
    const float* Hsrc = H2 + (size_t)(g * 256) * ldH + c0;
    const float* Hdst = H2 + (size_t)(g * 256) * ldH + cin + c0;
    for (int i = 0; i < 16; i++) {
        const int vl = qz * 64 + i * 4 + nl;
        {
            const float* ep = es + (size_t)(g * 256 + vl) * 128;
            esl[nl][c] = ep[c];
            esl[nl][64 + c] = ep[64 + c];
        }
        __syncthreads();
        if (act) {
            float hd = Hdst[(size_t)vl * ldH + c];
            float sum = 0.f, sq = 0.f, mx = -INFINITY;
#pragma unroll
            for (int e = 0; e < 8; e++) {
                int sl = srcl[(i * 4 + nl) * 8 + e];
                float m = hd + Hsrc[(size_t)sl * ldH + c];
                float4 e0 = *(const float4*)&esl[nl][e * 16 + 0];
                float4 e1 = *(const float4*)&esl[nl][e * 16 + 4];
                float4 e2 = *(const float4*)&esl[nl][e * 16 + 8];
                float4 e3 = *(const float4*)&esl[nl][e * 16 + 12];
                m = fmaf(e0.x, wreg[0], m);  m = fmaf(e0.y, wreg[1], m);
                m = fmaf(e0.z, wreg[2], m);  m = fmaf(e0.w, wreg[3], m);
                m = fmaf(e1.x, wreg[4], m);  m = fmaf(e1.y, wreg[5], m);
                m = fmaf(e1.z, wreg[6], m);  m = fmaf(e1.w, wreg[7], m);
                m = fmaf(e2.x, wreg[8], m);  m = fmaf(e2.y, wreg[9], m);
                m = fmaf(e2.z, wreg[10], m); m = fmaf(e2.w, wreg[11], m);
                m = fmaf(e3.x, wreg[12], m); m = fmaf(e3.y, wreg[13], m);
                m = fmaf(e3.z, wreg[14], m); m = fmaf(e3.w, wreg[15], m);
                sum += m;
                sq = fmaf(m, m, sq);
                mx = fmaxf(mx, m);
            }
            float mean = sum * 0.125f, msq = sq * 0.125f;
            float stdv = sqrtf(fmaxf(msq - mean * mean, 0.f) + 1e-30f);
            size_t o = (size_t)(g * 256 + vl) * ldX + offX + cc;
            unsigned short h;
            h = f2bf(sum);  Xh[o] = h;            Xl[o] = f2bf(sum - bf2f(h));
            h = f2bf(mx);   Xh[o + cin] = h;      Xl[o + cin] = f2bf(mx - bf2f(h));
            h = f2bf(stdv); Xh[o + 2 * cin] = h;  Xl[o + 2 * cin] = f2bf(stdv - bf2f(h));
        }
        __syncthreads();
    }
}

// ======================= BatchNorm stats (deterministic, split-bf16 input) ===========
__global__ void bnstats1s_k(const unsigned short* __restrict__ uh, const unsigned short* __restrict__ ul,
                            float* __restrict__ part, int cout)
{
    int c = threadIdx.x;
    if (c >= cout) return;
    int r0 = blockIdx.x * 256;
    float s = 0.f, q = 0.f;
    for (int r = r0; r < r0 + 256; r++) {
        size_t o = (size_t)r * cout + c;
        float v = bf2f(uh[o]) + bf2f(ul[o]);
        s += v;
        q = fmaf(v, v, q);
    }
    part[(size_t)blockIdx.x * cout + c] = s;
    part[(size_t)(64 + blockIdx.x) * cout + c] = q;
}

__global__ void bnstats2_k(const float* __restrict__ part, const float* __restrict__ bng,
                           const float* __restrict__ bnb, float* __restrict__ scale,
                           float* __restrict__ shift, int cout)
{
    int c = threadIdx.x;
    if (c >= cout) return;
    float s = 0.f, q = 0.f;
    for (int b = 0; b < 64; b++) { s += part[(size_t)b * cout + c]; q += part[(size_t)(64 + b) * cout + c]; }
    float mean = s / 16384.f;
    float var  = q / 16384.f - mean * mean;
    float sc   = bng[c] / sqrtf(var + 1e-5f);
    scale[c] = sc;
    shift[c] = bnb[c] - mean * sc;
}

// ======================= head =======================
__global__ void rowmax_k(const float* __restrict__ h3, float* __restrict__ nm)
{
    int wave = threadIdx.x >> 6;
    int lane = threadIdx.x & 63;
    int node = blockIdx.x * 4 + wave;
    const float* row = h3 + (size_t)node * 192;
    float m = -INFINITY;
    for (int t = lane; t < 192; t += 64) m = fmaxf(m, row[t]);
#pragma unroll
    for (int off = 32; off > 0; off >>= 1) m = fmaxf(m, __shfl_down(m, off, 64));
    if (lane == 0) nm[node] = m;
}

__global__ __launch_bounds__(256) void g_k(const float* __restrict__ nm,
    const float* __restrict__ W3, const float* __restrict__ b3,
    const float* __restrict__ W4, const float* __restrict__ b4,
    float* __restrict__ g)
{
    __shared__ float row[256];
    __shared__ float t1[64];
    int b = blockIdx.x, tid = threadIdx.x;
    row[tid] = nm[b * 256 + tid];
    __syncthreads();
    if (tid < 64) {
        float a = b3[tid];
        for (int k = 0; k < 256; k++) a = fmaf(row[k], W3[k * 64 + tid], a);
        t1[tid] = fmaxf(a, 0.f);
    }
    __syncthreads();
    float a = b4[tid];
    for (int j = 0; j < 64; j++) a = fmaf(t1[j], W4[j * 256 + tid], a);
    g[b * 256 + tid] = 1.f / (1.f + expf(-a));
}

// ======================= masked softmax (parallel, 2-pass) =======================
__global__ __launch_bounds__(256) void sm1_k(const float* __restrict__ mask,
    const float* __restrict__ g, const float* __restrict__ h3, float* __restrict__ part)
{
    int b = blockIdx.x, s = blockIdx.y, tid = threadIdx.x;
    float l[24];
#pragma unroll
    for (int t = 0; t < 24; t++) {
        int i = s * 6144 + t * 256 + tid;
        size_t idx = (size_t)b * 49152 + i;
        float mk = mask[idx];
        l[t] = (mk == 0.f) ? -1e5f : g[b * 256 + i / 192] * h3[idx];
    }
    float m = -INFINITY;
#pragma unroll
    for (int t = 0; t < 24; t++) m = fmaxf(m, l[t]);
    __shared__ float red[256];
    red[tid] = m; __syncthreads();
    for (int st = 128; st > 0; st >>= 1) { if (tid < st) red[tid] = fmaxf(red[tid], red[tid + st]); __syncthreads(); }
    m = red[0]; __syncthreads();
    float z = 0.f;
#pragma unroll
    for (int t = 0; t < 24; t++) z += expf(l[t] - m);
    red[tid] = z; __syncthreads();
    for (int st = 128; st > 0; st >>= 1) { if (tid < st) red[tid] += red[tid + st]; __syncthreads(); }
    if (tid == 0) { part[(b * 8 + s) * 2] = m; part[(b * 8 + s) * 2 + 1] = red[0]; }
}

__global__ void sm2_k(const float* __restrict__ part, float* __restrict__ mz)
{
    int b = threadIdx.x;
    if (b >= 64) return;
    float M = -INFINITY;
    for (int s = 0; s < 8; s++) M = fmaxf(M, part[(b * 8 + s) * 2]);
    float Z = 0.f;
    for (int s = 0; s < 8; s++) Z += part[(b * 8 + s) * 2 + 1] * expf(part[(b * 8 + s) * 2] - M);
    mz[b * 2] = M;
    mz[b * 2 + 1] = 1.f / Z;
}

__global__ __launch_bounds__(256) void sm3_k(const float* __restrict__ mask,
    const float* __restrict__ g, const float* __restrict__ h3,
    const float* __restrict__ mz, float* __restrict__ out)
{
    int b = blockIdx.x, s = blockIdx.y, tid = threadIdx.x;
    float M = mz[b * 2], invZ = mz[b * 2 + 1];
#pragma unroll
    for (int t = 0; t < 24; t++) {
        int i = s * 6144 + t * 256 + tid;
        size_t idx = (size_t)b * 49152 + i;
        float mk = mask[idx];
        float v = (mk == 0.f) ? -1e5f : g[b * 256 + i / 192] * h3[idx];
        out[idx] = expf(v - M) * invZ;
    }
}

// ======================= launcher =======================
extern "C" void kernel_launch(void* const* d_in, const int* in_sizes, int n_in,
                              void* d_out, int out_size, void* d_ws, size_t ws_size,
                              hipStream_t stream)
{
    const float* ns   = (const float*)d_in[0];
    const float* es   = (const float*)d_in[1];
    const float* dm   = (const float*)d_in[2];
    const float* mask = (const float*)d_in[3];
    const int*   src  = (const int*)d_in[4];
    const float* Wm1 = (const float*)d_in[6],  *bm1 = (const float*)d_in[7];
    const float* Wu1 = (const float*)d_in[8],  *bu1 = (const float*)d_in[9];
    const float* bng1= (const float*)d_in[10], *bnb1= (const float*)d_in[11];
    const float* Wx1 = (const float*)d_in[12], *bx1 = (const float*)d_in[13];
    const float* Wm2 = (const float*)d_in[14], *bm2 = (const float*)d_in[15];
    const float* Wu2 = (const float*)d_in[16], *bu2 = (const float*)d_in[17];
    const float* bng2= (const float*)d_in[18], *bnb2= (const float*)d_in[19];
    const float* Wx2 = (const float*)d_in[20], *bx2 = (const float*)d_in[21];
    const float* Wm3 = (const float*)d_in[22], *bm3 = (const float*)d_in[23];
    const float* Wu3 = (const float*)d_in[24], *bu3 = (const float*)d_in[25];
    const float* bng3= (const float*)d_in[26], *bnb3= (const float*)d_in[27];
    const float* Wx3 = (const float*)d_in[28], *bx3 = (const float*)d_in[29];
    const float* W1 = (const float*)d_in[30], *b1 = (const float*)d_in[31];
    const float* W2 = (const float*)d_in[32], *b2 = (const float*)d_in[33];
    const float* W3 = (const float*)d_in[34], *b3 = (const float*)d_in[35];
    const float* W4 = (const float*)d_in[36], *b4 = (const float*)d_in[37];
    float* out = (float*)d_out;

    const int N = NNODE;
    char* base = (char*)d_ws;
    size_t off = 0;
    auto alloc = [&](size_t bytes) -> void* {
        void* p = base + off;
        off = (off + bytes + 255) & ~(size_t)255;
        return p;
    };
    // X: one buffer reused as X1 (ld512) -> X2 (ld1664) -> X3 (ld1536); live ranges disjoint
    unsigned short* Xh = (unsigned short*)alloc((size_t)N * 1664 * 2);
    unsigned short* Xl = (unsigned short*)alloc((size_t)N * 1664 * 2);
    float* H2   = (float*)alloc((size_t)N * 832 * 4);          // also dm-tmp before L1
    unsigned short* uh = (unsigned short*)alloc((size_t)N * 384 * 2);
    unsigned short* ul = (unsigned short*)alloc((size_t)N * 384 * 2);
    float* h3b  = (float*)alloc((size_t)N * 192 * 4);
    float* d2f  = (float*)alloc((size_t)N * 32 * 4);
    float* part = (float*)alloc((size_t)128 * 384 * 4);
    float* scale= (float*)alloc(384 * 4);
    float* shift= (float*)alloc(384 * 4);
    float* bias2= (float*)alloc(384 * 4);
    float* biasH1 = (float*)alloc(256 * 4);
    float* biasH2 = (float*)alloc(832 * 4);
    float* biasH3 = (float*)alloc(768 * 4);
    float* nm   = (float*)alloc((size_t)N * 4);
    float* gbuf = (float*)alloc((size_t)N * 4);
    float* smp  = (float*)alloc(64 * 8 * 2 * 4);
    float* smz  = (float*)alloc(64 * 2 * 4);
    auto aw = [&](size_t elems) -> unsigned short* { return (unsigned short*)alloc(elems * 2); };
    unsigned short *BWm1h = aw(256 * 128),   *BWm1l = aw(256 * 128);
    unsigned short *BWu1h = aw(384 * 512),   *BWu1l = aw(384 * 512);
    unsigned short *BWx1h = aw(384 * 384),   *BWx1l = aw(384 * 384);
    unsigned short *BWm2h = aw(896 * 448),   *BWm2l = aw(896 * 448);
    unsigned short *BWu2h = aw(384 * 1664),  *BWu2l = aw(384 * 1664);
    unsigned short *BWx2h = aw(384 * 384),   *BWx2l = aw(384 * 384);
    unsigned short *BWm3h = aw(768 * 384),   *BWm3l = aw(768 * 384);
    unsigned short *BWu3h = aw(256 * 1536),  *BWu3l = aw(256 * 1536);
    unsigned short *BWx3h = aw(256 * 192),   *BWx3l = aw(256 * 192);

    auto gp = [](size_t n) { return dim3((unsigned)((n + 255) / 256)); };

    // ---- weight prep (independent) ----
    prep_bt<<<gp(128 * 128), 256, 0, stream>>>(Wm1,             BWm1h,             BWm1l,             128, 128, 128, 128);
    prep_bt<<<gp(128 * 128), 256, 0, stream>>>(Wm1 + 128 * 128, BWm1h + 128 * 128, BWm1l + 128 * 128, 128, 128, 128, 128);
    prep_wu<<<gp(384 * 512), 256, 0, stream>>>(Wu1, BWu1h, BWu1l, 128, 384, 384);
    prep_bt<<<gp(416 * 448), 256, 0, stream>>>(Wm2,             BWm2h,             BWm2l,             416, 416, 448, 416);
    prep_bt<<<gp(480 * 448), 256, 0, stream>>>(Wm2 + 416 * 416, BWm2h + 416 * 448, BWm2l + 416 * 448, 416, 416, 448, 480);
    prep_wu<<<gp(384 * 1664), 256, 0, stream>>>(Wu2, BWu2h, BWu2l, 416, 384, 384);
    prep_bt<<<gp(384 * 384), 256, 0, stream>>>(Wm3,             BWm3h,             BWm3l,             384, 384, 384, 384);
    prep_bt<<<gp(384 * 384), 256, 0, stream>>>(Wm3 + 384 * 384, BWm3h + 384 * 384, BWm3l + 384 * 384, 384, 384, 384, 384);
    prep_wu<<<gp(256 * 1536), 256, 0, stream>>>(Wu3, BWu3h, BWu3l, 384, 192, 256);
    prep_biasH<<<gp(256), 256, 0, stream>>>(bm1, biasH1, 128);
    prep_biasH<<<gp(832), 256, 0, stream>>>(bm2, biasH2, 416);
    prep_biasH<<<gp(768), 256, 0, stream>>>(bm3, biasH3, 384);

    // ---- ns -> X1 h-part (ld 512, off 0) ----
    csplit_k<<<gp((size_t)N * 128), 256, 0, stream>>>(ns, 128, 128, Xh, Xl, 512, 0);

    // ---- d2 = (dm@W1+b1)@W2+b2 (fp32; H2 as tmp [N,64]) ----
    gemm_k<<<dim3(1, 128), 256, 0, stream>>>(dm, W1, H2, 64, 256, b1);
    gemm_k<<<dim3(1, 128), 256, 0, stream>>>(H2, W2, d2f, 32, 64, b2);

    // ================= layer 1 (cin=128, X ld 512) =================
    mgemm2<0, 0><<<dim3(128, 2), 256, 0, stream>>>(Xh, Xl, 512, 128, BWm1h, BWm1l, 128,
                                                   H2, nullptr, nullptr, 256, 256, biasH1);
    agg2_k<<<dim3(64, 2, 4), 256, 0, stream>>>(H2, es, src, Wm1 + 2 * 128 * 128, Xh, Xl, 128, 256, 512, 128);
    mgemm2<0, 1><<<dim3(128, 3), 256, 0, stream>>>(Xh, Xl, 512, 512, BWu1h, BWu1l, 512,
                                                   nullptr, uh, ul, 384, 384, bu1);
    bnstats1s_k<<<64, 384, 0, stream>>>(uh, ul, part, 384);
    bnstats2_k<<<1, 384, 0, stream>>>(part, bng1, bnb1, scale, shift, 384);
    prep_wx<<<gp(384 * 384), 256, 0, stream>>>(Wx1, scale, BWx1h, BWx1l, 384, 384, 384, 384);
    bias2_k<<<gp(384), 256, 0, stream>>>(Wx1, bx1, shift, bias2, 384, 384);
    mgemm2<1, 1><<<dim3(128, 3), 256, 0, stream>>>(uh, ul, 384, 384, BWx1h, BWx1l, 384,
                                                   nullptr, Xh, Xl, 1664, 384, bias2);  // h2a -> X2[0:384)
    csplit_k<<<gp((size_t)N * 32), 256, 0, stream>>>(d2f, 32, 32, Xh, Xl, 1664, 384);   // d2 -> X2[384:416)

    // ================= layer 2 (cin=416, X ld 1664) =================
    mgemm2<0, 0><<<dim3(128, 7), 256, 0, stream>>>(Xh, Xl, 1664, 416, BWm2h, BWm2l, 448,
                                                   H2, nullptr, nullptr, 832, 832, biasH2);
    agg2_k<<<dim3(64, 7, 4), 256, 0, stream>>>(H2, es, src, Wm2 + 2 * 416 * 416, Xh, Xl, 416, 832, 1664, 416);
    mgemm2<0, 1><<<dim3(128, 3), 256, 0, stream>>>(Xh, Xl, 1664, 1664, BWu2h, BWu2l, 1664,
                                                   nullptr, uh, ul, 384, 384, bu2);
    bnstats1s_k<<<64, 384, 0, stream>>>(uh, ul, part, 384);
    bnstats2_k<<<1, 384, 0, stream>>>(part, bng2, bnb2, scale, shift, 384);
    prep_wx<<<gp(384 * 384), 256, 0, stream>>>(Wx2, scale, BWx2h, BWx2l, 384, 384, 384, 384);
    bias2_k<<<gp(384), 256, 0, stream>>>(Wx2, bx2, shift, bias2, 384, 384);
    mgemm2<1, 1><<<dim3(128, 3), 256, 0, stream>>>(uh, ul, 384, 384, BWx2h, BWx2l, 384,
                                                   nullptr, Xh, Xl, 1536, 384, bias2);  // h3-in -> X3[0:384)

    // ================= layer 3 (cin=384, X ld 1536) =================
    mgemm2<0, 0><<<dim3(128, 6), 256, 0, stream>>>(Xh, Xl, 1536, 384, BWm3h, BWm3l, 384,
                                                   H2, nullptr, nullptr, 768, 768, biasH3);
    agg2_k<<<dim3(64, 6, 4), 256, 0, stream>>>(H2, es, src, Wm3 + 2 * 384 * 384, Xh, Xl, 384, 768, 1536, 384);
    mgemm2<0, 1><<<dim3(128, 2), 256, 0, stream>>>(Xh, Xl, 1536, 1536, BWu3h, BWu3l, 1536,
                                                   nullptr, uh, ul, 192, 192, bu3);
    bnstats1s_k<<<64, 384, 0, stream>>>(uh, ul, part, 192);
    bnstats2_k<<<1, 384, 0, stream>>>(part, bng3, bnb3, scale, shift, 192);
    prep_wx<<<gp(256 * 192), 256, 0, stream>>>(Wx3, scale, BWx3h, BWx3l, 192, 192, 192, 256);
    bias2_k<<<gp(192), 256, 0, stream>>>(Wx3, bx3, shift, bias2, 192, 192);
    mgemm2<2, 0><<<dim3(128, 2), 256, 0, stream>>>(uh, ul, 192, 192, BWx3h, BWx3l, 192,
                                                   h3b, nullptr, nullptr, 192, 192, bias2);

    // ---- head ----
    rowmax_k<<<N / 4, 256, 0, stream>>>(h3b, nm);
    g_k<<<64, 256, 0, stream>>>(nm, W3, b3, W4, b4, gbuf);
    sm1_k<<<dim3(64, 8), 256, 0, stream>>>(mask, gbuf, h3b, smp);
    sm2_k<<<1, 64, 0, stream>>>(smp, smz);
    sm3_k<<<dim3(64, 8), 256, 0, stream>>>(mask, gbuf, h3b, smz, out);
}